// Round 12
// baseline (451.581 us; speedup 1.0000x reference)
//
#include <hip/hip_runtime.h>
#include <hip/hip_cooperative_groups.h>
#include <math.h>

namespace cg = cooperative_groups;

#define N_NODES 100000
#define F_IN    128
#define H1      8
#define C1      16
#define D1      128   // H1*C1
#define NCLS    40
#define NEG     0.2f

typedef unsigned int uint32;
typedef unsigned short ushort16;
typedef float v2f __attribute__((ext_vector_type(2)));
typedef __attribute__((ext_vector_type(8))) short bf16x8;   // 4 VGPRs, MFMA A/B frag
typedef __attribute__((ext_vector_type(4))) float f32x4;    // MFMA C/D frag

__device__ __forceinline__ ushort16 f2bf(float f) {
    unsigned int u = __float_as_uint(f);
    u += 0x7fffu + ((u >> 16) & 1u);          // round-to-nearest-even
    return (ushort16)(u >> 16);
}
__device__ __forceinline__ float bf_lo(uint32 p) { return __uint_as_float(p << 16); }
__device__ __forceinline__ float bf_hi(uint32 p) { return __uint_as_float(p & 0xffff0000u); }

#define NG 1563   // gemm blocks (64 rows each)
#define NB_SCAN 391  // ceil(N_NODES/256)

// W1 -> bf16 transposed+padded [128][136]; W2 -> bf16 transposed+padded
// [48][136] (cols 40-47 zero); also zeroes deg (replaces memset).
__global__ void prep_w_kernel(const float* __restrict__ W1,
                              const float* __restrict__ W2,
                              unsigned short* __restrict__ w1t,
                              unsigned short* __restrict__ w2t,
                              int* __restrict__ deg)
{
    int idx = blockIdx.x * 256 + threadIdx.x;
    if (idx < 16384) {
        int n = idx & 127, k = idx >> 7;        // coalesced read of W1[k][n]
        w1t[n * 136 + k] = f2bf(W1[k * 128 + n]);
    }
    if (idx < 6528) {                           // 48 x 136
        int c = idx / 136, k = idx - 136 * c;
        unsigned short v = 0;
        if (c < 40 && k < 128) v = f2bf(W2[k * 40 + c]);
        w2t[idx] = v;
    }
    if (idx < N_NODES) deg[idx] = 0;
}

// ---------------- fused: layer-1 MFMA GEMM(+logits) blocks + CSR-count ------
// Proven 1:4 interleave, 1 edge/thread: atomic-throughput-bound count blocks
// co-resident with LDS/MFMA-bound gemm blocks from t=0.
__global__ __launch_bounds__(256) void gemm1_count_kernel(
    const float* __restrict__ x, const unsigned short* __restrict__ w1t,
    uint32* __restrict__ h8,            // fp8 rows, N x 32 dwords
    const float* __restrict__ a_src, const float* __restrict__ a_dst,
    float* __restrict__ ssrc, float* __restrict__ sdst,
    const int* __restrict__ ei, int E,
    int* __restrict__ deg, int* __restrict__ rank)
{
    // 34816 B: holds W1^T bf16 [128][136] during MFMA, then hs fp32 [64][132]
    __shared__ __align__(16) uint32 wbuf[8704];
    const int bid = blockIdx.x;
    const int tid = threadIdx.x;
    const bool is_gemm = ((bid % 5) == 0) && (bid / 5 < NG);
    if (!is_gemm) {
        // ---------------- count path: rank[e] = old deg[dst]++ --------------
        int ng_before = bid / 5 + ((bid % 5) ? 1 : 0);   // gemm blocks < bid
        if (ng_before > NG) ng_before = NG;
        int c = bid - ng_before;
        long long e = (long long)c * 256 + tid;
        if (e < E) rank[e] = atomicAdd(&deg[ei[E + e]], 1);
        return;
    }
    const int row0 = (bid / 5) * 64;
    const int wid = tid >> 6, lane = tid & 63;

    // ---- A fragments straight from global: wave w owns rows 16w..16w+15.
    const int arow = row0 + wid * 16 + (lane & 15);
    const bool rowok = arow < N_NODES;
    const float* xp = x + (size_t)arow * 128 + 8 * (lane >> 4);
    float4 af0[4], af1[4];
#pragma unroll
    for (int s = 0; s < 4; ++s) {
        if (rowok) {
            af0[s] = *(const float4*)(xp + 32 * s);
            af1[s] = *(const float4*)(xp + 32 * s + 4);
        } else {
            af0[s] = make_float4(0.f, 0.f, 0.f, 0.f);
            af1[s] = make_float4(0.f, 0.f, 0.f, 0.f);
        }
    }
    // ---- stage W1^T bf16 into LDS (linear 34816 B copy, pad included) ----
    {
        const uint32* g = (const uint32*)w1t;
#pragma unroll
        for (int i = 0; i < 8; ++i)
            ((uint4*)wbuf)[tid + i * 256] = ((const uint4*)g)[tid + i * 256];
        wbuf[8192 + tid] = g[8192 + tid];
        wbuf[8448 + tid] = g[8448 + tid];
    }
    // ---- convert A to bf16 fragments (same k-order as B reads: 8g+j) ----
    bf16x8 a[4];
#pragma unroll
    for (int s = 0; s < 4; ++s) {
        a[s][0] = (short)f2bf(af0[s].x); a[s][1] = (short)f2bf(af0[s].y);
        a[s][2] = (short)f2bf(af0[s].z); a[s][3] = (short)f2bf(af0[s].w);
        a[s][4] = (short)f2bf(af1[s].x); a[s][5] = (short)f2bf(af1[s].y);
        a[s][6] = (short)f2bf(af1[s].z); a[s][7] = (short)f2bf(af1[s].w);
    }
    __syncthreads();
    // ---- K loop: 4 steps x 8 col-fragments = 32 MFMAs / wave ----
    f32x4 acc[8];
#pragma unroll
    for (int j = 0; j < 8; ++j)
#pragma unroll
        for (int r = 0; r < 4; ++r) acc[j][r] = 0.f;
    const unsigned short* wb = (const unsigned short*)wbuf;
    const int bc = lane & 15, ko = 8 * (lane >> 4);
#pragma unroll
    for (int s = 0; s < 4; ++s) {
#pragma unroll
        for (int j = 0; j < 8; ++j) {
            bf16x8 b = *(const bf16x8*)&wb[(16 * j + bc) * 136 + 32 * s + ko];
            acc[j] = __builtin_amdgcn_mfma_f32_16x16x32_bf16(a[s], b, acc[j], 0, 0, 0);
        }
    }
    __syncthreads();   // all MFMA operand reads of wbuf done
    // ---- write acc to hs[64][132] (C/D map: col=lane&15, row=(lane>>4)*4+r)
    float* hs = (float*)wbuf;
    const int cr0 = wid * 16 + 4 * (lane >> 4);
#pragma unroll
    for (int j = 0; j < 8; ++j)
#pragma unroll
        for (int r = 0; r < 4; ++r)
            hs[(cr0 + r) * 132 + 16 * j + bc] = acc[j][r];
    __syncthreads();
    // ---- fp8 pack: 64 rows x 16 uint2-groups, 4 tasks/thread ----
#pragma unroll
    for (int t = 0; t < 4; ++t) {
        int task = tid + t * 256;     // 0..1023
        int r = task >> 4, g = task & 15;
        if (row0 + r < N_NODES) {
            float4 va = *(const float4*)&hs[r * 132 + 8 * g];
            float4 vb = *(const float4*)&hs[r * 132 + 8 * g + 4];
            int p0 = __builtin_amdgcn_cvt_pk_fp8_f32(va.x, va.y, 0, false);
            p0     = __builtin_amdgcn_cvt_pk_fp8_f32(va.z, va.w, p0, true);
            int p1 = __builtin_amdgcn_cvt_pk_fp8_f32(vb.x, vb.y, 0, false);
            p1     = __builtin_amdgcn_cvt_pk_fp8_f32(vb.z, vb.w, p1, true);
            uint2 pk; pk.x = (uint32)p0; pk.y = (uint32)p1;
            ((uint2*)h8)[(size_t)(row0 + r) * 16 + g] = pk;
        }
    }
    // ---- logits: 64 rows x 8 heads = 512 tasks, 2 per thread ----
#pragma unroll
    for (int t = 0; t < 2; ++t) {
        int task = tid + t * 256;
        int r = task >> 3, hh = task & 7;
        if (row0 + r < N_NODES) {
            float as = 0.f, ad = 0.f;
#pragma unroll
            for (int c = 0; c < 16; ++c) {
                float v = hs[r * 132 + hh * 16 + c];
                as = fmaf(v, a_src[hh * 16 + c], as);
                ad = fmaf(v, a_dst[hh * 16 + c], ad);
            }
            ssrc[(row0 + r) * 8 + hh] = as;
            sdst[(row0 + r) * 8 + hh] = ad;
        }
    }
}

// ---------------- CSR finish: scan1 + scan3 + scatter, one cooperative ------
// Removes two dispatch boundaries + inter-kernel drains in the serial chain.
__global__ void csr_kernel(const int* __restrict__ deg,
                           int* __restrict__ incl,
                           int* __restrict__ bsum,
                           int* __restrict__ offsets,
                           const int* __restrict__ ei, int E,
                           const int* __restrict__ rank,
                           int* __restrict__ srcs)
{
    cg::grid_group grid = cg::this_grid();
    // ---- phase 1: block-local inclusive scan + block sums ----
    {
        __shared__ int tmp[256];
        int i = blockIdx.x * 256 + threadIdx.x;
        int v = (i < N_NODES) ? deg[i] : 0;
        tmp[threadIdx.x] = v;
        __syncthreads();
        for (int o = 1; o < 256; o <<= 1) {
            int t = (threadIdx.x >= (unsigned)o) ? tmp[threadIdx.x - o] : 0;
            __syncthreads();
            tmp[threadIdx.x] += t;
            __syncthreads();
        }
        if (i < N_NODES) incl[i] = tmp[threadIdx.x];
        if (threadIdx.x == 255) bsum[blockIdx.x] = tmp[255];
    }
    grid.sync();
    // ---- phase 2: offsets[i+1] = incl[i] + prefix(bsum, block) ----
    {
        __shared__ int red[4];
        int pre = 0;
        for (int i = threadIdx.x; i < blockIdx.x; i += 256) pre += bsum[i];
#pragma unroll
        for (int o = 32; o > 0; o >>= 1) pre += __shfl_xor(pre, o);
        if ((threadIdx.x & 63) == 0) red[threadIdx.x >> 6] = pre;
        __syncthreads();
        int total = red[0] + red[1] + red[2] + red[3];
        int i = blockIdx.x * 256 + threadIdx.x;
        if (i < N_NODES) offsets[i + 1] = incl[i] + total;
        if (i == 0) offsets[0] = 0;
    }
    grid.sync();
    // ---- phase 3: atomic-free scatter (grid-stride) ----
    {
        const int stride = gridDim.x * 256;
        for (int e = blockIdx.x * 256 + threadIdx.x; e < E; e += stride) {
            int s = ei[e], d = ei[E + e];
            srcs[offsets[d] + rank[e]] = s;
        }
    }
}

// ---------------- layer 1 gather: one wave per dst node (fp8 h rows) --------
// 128-thread blocks. Widened inner loop: 16 lanes cover a row in uint2s
// (8 ch/lane), 4 edges in flight per step -> 2 steps / 8-edge chunk.
__global__ void gather1_kernel(const uint32* __restrict__ h8,   // N x 32 dwords
                               const float* __restrict__ ssrc,
                               const float* __restrict__ sdst,
                               const int* __restrict__ offsets,
                               const int* __restrict__ srcs,
                               const float* __restrict__ b1,
                               uint32* __restrict__ h1b)        // N x 64 dwords
{
    __shared__ uint2 sw[2][64];
    int d = (blockIdx.x * blockDim.x + threadIdx.x) >> 6;
    int lane = threadIdx.x & 63;
    int wid = (threadIdx.x >> 6) & 1;
    if (d >= N_NODES) return;
    const int hw = lane & 7;            // head in weight phase
    const int u2 = lane & 15;           // uint2 in row: channels 8u2..8u2+7
    const int qt = lane >> 4;           // quarter: which of 4 in-flight edges
    const int hc = u2 >> 1;             // head of my channels
    const float sd_w = sdst[d * H1 + hw];

    float a0 = 0.f, a1 = 0.f, a2 = 0.f, a3 = 0.f;
    float a4 = 0.f, a5 = 0.f, a6 = 0.f, a7 = 0.f;
    float wsum = 0.f;

    // (s,w) staging slot for my (quarter, head): edge of slot = 4t+qt
    const uint2* swp = &sw[wid][(qt << 3) | hc];
    const uint2* h8v = (const uint2*)h8;       // rows of 16 uint2
    const int beg = offsets[d], end = offsets[d + 1];
    for (int base = beg; base < end; base += 8) {
        int cnt = end - base; if (cnt > 8) cnt = 8;
        int s_l = 0; float w_l = 0.f;
        if ((lane >> 3) < cnt) {
            s_l = srcs[base + (lane >> 3)];
            float lg = ssrc[s_l * H1 + hw] + sd_w;
            lg = lg >= 0.f ? lg : NEG * lg;
            w_l = __expf(lg);
        }
        wsum += w_l;
        sw[wid][lane] = make_uint2((uint32)s_l, __float_as_uint(w_l));
        asm volatile("s_waitcnt lgkmcnt(0)" ::: "memory");
#pragma unroll
        for (int t = 0; t < 2; ++t) {       // slots >= cnt carry w=0, s=0
            uint2 q = swp[32 * t];
            float w = __uint_as_float(q.y);
            uint2 p = h8v[(size_t)q.x * 16 + u2];
            v2f xl = __builtin_amdgcn_cvt_pk_f32_fp8((int)p.x, false);
            v2f xh = __builtin_amdgcn_cvt_pk_f32_fp8((int)p.x, true);
            v2f yl = __builtin_amdgcn_cvt_pk_f32_fp8((int)p.y, false);
            v2f yh = __builtin_amdgcn_cvt_pk_f32_fp8((int)p.y, true);
            a0 = fmaf(w, xl[0], a0); a1 = fmaf(w, xl[1], a1);
            a2 = fmaf(w, xh[0], a2); a3 = fmaf(w, xh[1], a3);
            a4 = fmaf(w, yl[0], a4); a5 = fmaf(w, yl[1], a5);
            a6 = fmaf(w, yh[0], a6); a7 = fmaf(w, yh[1], a7);
        }
    }
    // head-wise weight totals: reduce over the 8 edge-slot groups (bits 3..5)
    wsum += __shfl_xor(wsum, 8);
    wsum += __shfl_xor(wsum, 16);
    wsum += __shfl_xor(wsum, 32);
    float wtot = __shfl(wsum, hc);       // before divergence
    // cross-quarter accumulator reduce (bits 4,5)
    a0 += __shfl_xor(a0, 16); a0 += __shfl_xor(a0, 32);
    a1 += __shfl_xor(a1, 16); a1 += __shfl_xor(a1, 32);
    a2 += __shfl_xor(a2, 16); a2 += __shfl_xor(a2, 32);
    a3 += __shfl_xor(a3, 16); a3 += __shfl_xor(a3, 32);
    a4 += __shfl_xor(a4, 16); a4 += __shfl_xor(a4, 32);
    a5 += __shfl_xor(a5, 16); a5 += __shfl_xor(a5, 32);
    a6 += __shfl_xor(a6, 16); a6 += __shfl_xor(a6, 32);
    a7 += __shfl_xor(a7, 16); a7 += __shfl_xor(a7, 32);
    if (lane < 16) {
        // self-loop weight + contribution for my head
        float lgs = ssrc[d * H1 + hc] + sdst[d * H1 + hc];
        lgs = lgs >= 0.f ? lgs : NEG * lgs;
        float wself = __expf(lgs);
        uint2 p = h8v[(size_t)d * 16 + u2];
        v2f xl = __builtin_amdgcn_cvt_pk_f32_fp8((int)p.x, false);
        v2f xh = __builtin_amdgcn_cvt_pk_f32_fp8((int)p.x, true);
        v2f yl = __builtin_amdgcn_cvt_pk_f32_fp8((int)p.y, false);
        v2f yh = __builtin_amdgcn_cvt_pk_f32_fp8((int)p.y, true);
        a0 = fmaf(wself, xl[0], a0); a1 = fmaf(wself, xl[1], a1);
        a2 = fmaf(wself, xh[0], a2); a3 = fmaf(wself, xh[1], a3);
        a4 = fmaf(wself, yl[0], a4); a5 = fmaf(wself, yl[1], a5);
        a6 = fmaf(wself, yh[0], a6); a7 = fmaf(wself, yh[1], a7);
        float inv = 1.f / (wself + wtot + 1e-16f);
        float4 bb0 = ((const float4*)b1)[2 * u2];
        float4 bb1 = ((const float4*)b1)[2 * u2 + 1];
        float r0 = fmaf(a0, inv, bb0.x); r0 = r0 > 0.f ? r0 : 0.f;
        float r1 = fmaf(a1, inv, bb0.y); r1 = r1 > 0.f ? r1 : 0.f;
        float r2 = fmaf(a2, inv, bb0.z); r2 = r2 > 0.f ? r2 : 0.f;
        float r3 = fmaf(a3, inv, bb0.w); r3 = r3 > 0.f ? r3 : 0.f;
        float r4 = fmaf(a4, inv, bb1.x); r4 = r4 > 0.f ? r4 : 0.f;
        float r5 = fmaf(a5, inv, bb1.y); r5 = r5 > 0.f ? r5 : 0.f;
        float r6 = fmaf(a6, inv, bb1.z); r6 = r6 > 0.f ? r6 : 0.f;
        float r7 = fmaf(a7, inv, bb1.w); r7 = r7 > 0.f ? r7 : 0.f;
        uint4 pk;
        pk.x = ((uint32)f2bf(r1) << 16) | (uint32)f2bf(r0);
        pk.y = ((uint32)f2bf(r3) << 16) | (uint32)f2bf(r2);
        pk.z = ((uint32)f2bf(r5) << 16) | (uint32)f2bf(r4);
        pk.w = ((uint32)f2bf(r7) << 16) | (uint32)f2bf(r6);
        ((uint4*)(h1b + (size_t)d * 64))[u2] = pk;
    }
}

// ---------------- layer 2 GEMM (bf16 MFMA) + logits, fused ------------------
__global__ __launch_bounds__(256) void gemm2_kernel(
    const uint32* __restrict__ h1b, const unsigned short* __restrict__ w2t,
    uint32* __restrict__ h2f8,          // fp8 rows, N x 10 dwords
    const float* __restrict__ a_src, const float* __restrict__ a_dst,
    float* __restrict__ ssrc, float* __restrict__ sdst)
{
    __shared__ __align__(16) unsigned short w2s[6528];   // 13056 B
    const int row0 = blockIdx.x * 64;
    const int tid = threadIdx.x;
    const int wid = tid >> 6, lane = tid & 63;
    const int bc = lane & 15, g = lane >> 4;

    // ---- stage W2^T bf16 (3264 dwords) ----
    {
        const uint32* gs = (const uint32*)w2t;
        uint32* wsd = (uint32*)w2s;
        for (int i = tid; i < 3264; i += 256) wsd[i] = gs[i];
    }
    // ---- A fragments: wave w owns rows 16w..16w+15, direct bf16 loads ----
    const int arow = row0 + wid * 16 + bc;
    const bool rowok = arow < N_NODES;
    bf16x8 a[4];
#pragma unroll
    for (int s = 0; s < 4; ++s) {
        uint4 v = make_uint4(0u, 0u, 0u, 0u);
        if (rowok) v = *(const uint4*)&h1b[(size_t)arow * 64 + 16 * s + 4 * g];
        a[s] = *(bf16x8*)&v;
    }
    __syncthreads();
    // ---- 4 k-steps x 3 col-fragments = 12 MFMA / wave ----
    f32x4 acc[3];
#pragma unroll
    for (int j = 0; j < 3; ++j)
#pragma unroll
        for (int r = 0; r < 4; ++r) acc[j][r] = 0.f;
#pragma unroll
    for (int s = 0; s < 4; ++s) {
#pragma unroll
        for (int j = 0; j < 3; ++j) {
            bf16x8 b = *(const bf16x8*)&w2s[(16 * j + bc) * 136 + 32 * s + 8 * g];
            acc[j] = __builtin_amdgcn_mfma_f32_16x16x32_bf16(a[s], b, acc[j], 0, 0, 0);
        }
    }
    // ---- h2 fp8 pack: channels 4k..4k+3 live in adjacent bc-lanes ----
    const int cr0 = wid * 16 + 4 * g;
#pragma unroll
    for (int j = 0; j < 3; ++j)
#pragma unroll
        for (int r = 0; r < 4; ++r) {
            float v0 = acc[j][r];
            float v1 = __shfl_xor(v0, 1);
            float v2 = __shfl_xor(v0, 2);
            float v3 = __shfl_xor(v0, 3);
            if ((bc & 3) == 0) {
                int dw = 4 * j + (bc >> 2);          // dword index in row
                int row = row0 + cr0 + r;
                if (dw < 10 && row < N_NODES) {
                    int p = __builtin_amdgcn_cvt_pk_fp8_f32(v0, v1, 0, false);
                    p     = __builtin_amdgcn_cvt_pk_fp8_f32(v2, v3, p, true);
                    h2f8[(size_t)row * 10 + dw] = (uint32)p;
                }
            }
        }
    // ---- logits via bc-butterflies: 16 bc-lanes hold all cols of 4 rows ----
    float avs[3], avd[3];
#pragma unroll
    for (int j = 0; j < 3; ++j) {
        int col = 16 * j + bc;
        avs[j] = (col < NCLS) ? a_src[col] : 0.f;
        avd[j] = (col < NCLS) ? a_dst[col] : 0.f;
    }
    float ps[4], pd[4];
#pragma unroll
    for (int r = 0; r < 4; ++r) {
        float s_ = acc[0][r] * avs[0];
        s_ = fmaf(acc[1][r], avs[1], s_);
        s_ = fmaf(acc[2][r], avs[2], s_);
        float d_ = acc[0][r] * avd[0];
        d_ = fmaf(acc[1][r], avd[1], d_);
        d_ = fmaf(acc[2][r], avd[2], d_);
        ps[r] = s_; pd[r] = d_;
    }
#pragma unroll
    for (int o = 1; o < 16; o <<= 1) {
#pragma unroll
        for (int r = 0; r < 4; ++r) {
            ps[r] += __shfl_xor(ps[r], o);
            pd[r] += __shfl_xor(pd[r], o);
        }
    }
    if (bc < 4) {
        int row = row0 + cr0 + bc;
        if (row < N_NODES) {
            float vs = bc == 0 ? ps[0] : bc == 1 ? ps[1] : bc == 2 ? ps[2] : ps[3];
            float vd = bc == 0 ? pd[0] : bc == 1 ? pd[1] : bc == 2 ? pd[2] : pd[3];
            ssrc[row] = vs;
            sdst[row] = vd;
        }
    }
}

// ---------------- layer 2 gather + log_softmax: one wave per node (fp8) -----
__global__ void gather2_kernel(const uint32* __restrict__ h2f8, // N x 10 dwords
                               const float* __restrict__ ssrc,
                               const float* __restrict__ sdst,
                               const int* __restrict__ offsets,
                               const int* __restrict__ srcs,
                               const float* __restrict__ b2,
                               float* __restrict__ out)
{
    __shared__ uint2 sw[2][64];
    __shared__ __align__(16) float4 pacc[2][64];
    int d = (blockIdx.x * blockDim.x + threadIdx.x) >> 6;
    int lane = threadIdx.x & 63;
    int wid = (threadIdx.x >> 6) & 1;
    if (d >= N_NODES) return;
    const float sd = sdst[d];
    const int g = lane / 10;              // group 0..6 (g<6 accumulate)
    const int c = lane - 10 * g;          // dword within row: channels 4c..4c+3
    const bool act = lane < 10;           // lanes that own the output
    float acc0 = 0.f, acc1 = 0.f, acc2 = 0.f, acc3 = 0.f, wl = 0.f;

    // self-loop (output lanes only)
    float ws_self;
    {
        float lg = ssrc[d] + sd; lg = lg >= 0.f ? lg : NEG * lg;
        ws_self = __expf(lg);
        if (act) {
            uint32 p = h2f8[(size_t)d * 10 + lane];
            v2f lo = __builtin_amdgcn_cvt_pk_f32_fp8((int)p, false);
            v2f hi = __builtin_amdgcn_cvt_pk_f32_fp8((int)p, true);
            acc0 = ws_self * lo[0]; acc1 = ws_self * lo[1];
            acc2 = ws_self * hi[0]; acc3 = ws_self * hi[1];
        }
    }
    const int beg = offsets[d], end = offsets[d + 1];
    for (int base = beg; base < end; base += 64) {
        int cnt = end - base; if (cnt > 64) cnt = 64;
        int s_l = 0; float w_l = 0.f;
        if (lane < cnt) {
            s_l = srcs[base + lane];
            float lg = ssrc[s_l] + sd; lg = lg >= 0.f ? lg : NEG * lg;
            w_l = __expf(lg);
        }
        wl += w_l;
        sw[wid][lane] = make_uint2((uint32)s_l, __float_as_uint(w_l));
        asm volatile("s_waitcnt lgkmcnt(0)" ::: "memory");
        for (int j = 0; j < cnt; j += 6) {
            int jj = j + g;
            uint2 q = sw[wid][jj & 63];
            float w = ((g < 6) & (jj < cnt)) ? __uint_as_float(q.y) : 0.f;
            uint32 p = h2f8[(size_t)q.x * 10 + c];
            v2f lo = __builtin_amdgcn_cvt_pk_f32_fp8((int)p, false);
            v2f hi = __builtin_amdgcn_cvt_pk_f32_fp8((int)p, true);
            acc0 = fmaf(w, lo[0], acc0);
            acc1 = fmaf(w, lo[1], acc1);
            acc2 = fmaf(w, hi[0], acc2);
            acc3 = fmaf(w, hi[1], acc3);
        }
    }
    // denominator: one full-wave reduce at the end
    float t = wl;
#pragma unroll
    for (int o = 32; o > 0; o >>= 1) t += __shfl_xor(t, o);
    float ws = ws_self + t;
    // cross-group accumulator reduce via LDS (partials at lanes c + 10k)
    float4 mine; mine.x = acc0; mine.y = acc1; mine.z = acc2; mine.w = acc3;
    pacc[wid][lane] = mine;
    asm volatile("s_waitcnt lgkmcnt(0)" ::: "memory");
    float l0 = -INFINITY, l1 = -INFINITY, l2 = -INFINITY, l3 = -INFINITY;
    if (act) {
        float4 s0 = pacc[wid][lane];
        float4 s1 = pacc[wid][lane + 10];
        float4 s2 = pacc[wid][lane + 20];
        float4 s3 = pacc[wid][lane + 30];
        float4 s4 = pacc[wid][lane + 40];
        float4 s5 = pacc[wid][lane + 50];
        float a0 = s0.x + s1.x + s2.x + s3.x + s4.x + s5.x;
        float a1 = s0.y + s1.y + s2.y + s3.y + s4.y + s5.y;
        float a2 = s0.z + s1.z + s2.z + s3.z + s4.z + s5.z;
        float a3 = s0.w + s1.w + s2.w + s3.w + s4.w + s5.w;
        float inv = 1.f / (ws + 1e-16f);
        l0 = fmaf(a0, inv, b2[4 * lane + 0]);
        l1 = fmaf(a1, inv, b2[4 * lane + 1]);
        l2 = fmaf(a2, inv, b2[4 * lane + 2]);
        l3 = fmaf(a3, inv, b2[4 * lane + 3]);
    }
    // softmax over 10 active lanes: 16-lane butterflies suffice
    float m = fmaxf(fmaxf(l0, l1), fmaxf(l2, l3));
#pragma unroll
    for (int o = 8; o > 0; o >>= 1) m = fmaxf(m, __shfl_xor(m, o));
    float ex = act ? (__expf(l0 - m) + __expf(l1 - m) + __expf(l2 - m) + __expf(l3 - m)) : 0.f;
#pragma unroll
    for (int o = 8; o > 0; o >>= 1) ex += __shfl_xor(ex, o);
    float lse = __logf(ex) + m;
    if (act) {
        float4 r;
        r.x = l0 - lse; r.y = l1 - lse; r.z = l2 - lse; r.w = l3 - lse;
        ((float4*)(out + (size_t)d * NCLS))[lane] = r;
    }
}

extern "C" void kernel_launch(void* const* d_in, const int* in_sizes, int n_in,
                              void* d_out, int out_size, void* d_ws, size_t ws_size,
                              hipStream_t stream)
{
    const float* x   = (const float*)d_in[0];
    const int*   ei  = (const int*)  d_in[1];
    const float* W1  = (const float*)d_in[2];
    const float* as1 = (const float*)d_in[3];
    const float* ad1 = (const float*)d_in[4];
    const float* b1  = (const float*)d_in[5];
    const float* W2  = (const float*)d_in[6];
    const float* as2 = (const float*)d_in[7];
    const float* ad2 = (const float*)d_in[8];
    const float* b2  = (const float*)d_in[9];
    float* out = (float*)d_out;
    const int E = in_sizes[1] / 2;

    float* ws = (float*)d_ws;
    size_t off = 0;
    uint32* h1f8 = (uint32*)(ws + off); off += (size_t)N_NODES * 32;  // fp8 N x 128
    uint32* h1b = (uint32*)(ws + off); off += (size_t)N_NODES * 64;   // bf16 N x 128 packed
    float* ss1  = ws + off; off += (size_t)N_NODES * H1;
    float* sd1  = ws + off; off += (size_t)N_NODES * H1;
    uint32* h2f8 = (uint32*)(ws + off); off += (size_t)N_NODES * 10;  // fp8 N x 40
    float* ss2  = ws + off; off += N_NODES;
    float* sd2  = ws + off; off += N_NODES;
    unsigned short* w1t = (unsigned short*)(ws + off); off += 8704;   // bf16 W1^T [128][136]
    unsigned short* w2t = (unsigned short*)(ws + off); off += 3264;   // bf16 W2^T [48][136]
    int* ib = (int*)(ws + off);
    size_t ioff = 0;
    int* deg     = ib + ioff; ioff += N_NODES;      // zeroed in prep_w_kernel
    int* incl    = ib + ioff; ioff += N_NODES;
    int* offsets = ib + ioff; ioff += N_NODES + 1;
    int* bsum    = ib + ioff; ioff += 512;
    int* rank    = ib + ioff; ioff += E;
    int* srcs    = ib + ioff; ioff += E;

    const int nb = (N_NODES + 255) / 256;           // 391
    const int nc = (E + 255) / 256;                 // count blocks (6250)

    // W1/W2 -> bf16 transposed+padded + deg zeroing
    prep_w_kernel<<<nb, 256, 0, stream>>>(W1, W2, w1t, w2t, deg);

    // fused layer-1 MFMA gemm(+logits) + CSR count (proven 1:4 interleave)
    gemm1_count_kernel<<<NG + nc, 256, 0, stream>>>(x, w1t, h1f8, as1, ad1,
                                                    ss1, sd1, ei, E, deg, rank);

    // CSR finish: scan1+scan3+scatter, one cooperative launch
    {
        int Ev = E;
        void* cargs[] = { (void*)&deg, (void*)&incl, (void*)&bsum, (void*)&offsets,
                          (void*)&ei, (void*)&Ev, (void*)&rank, (void*)&srcs };
        hipLaunchCooperativeKernel((void*)csr_kernel, dim3(NB_SCAN), dim3(256),
                                   cargs, 0, stream);
    }

    // layer 1 gather (128-thread blocks, widened uint2 inner loop)
    gather1_kernel<<<(N_NODES * 64 + 127) / 128, 128, 0, stream>>>(h1f8, ss1, sd1, offsets, srcs, b1, h1b);

    // layer 2 (MFMA gemm + fp8 h2 pack + shuffle logits fused)
    gemm2_kernel<<<(N_NODES + 63) / 64, 256, 0, stream>>>(h1b, w2t, h2f8, as2, ad2, ss2, sd2);
    gather2_kernel<<<(N_NODES * 64 + 127) / 128, 128, 0, stream>>>(h2f8, ss2, sd2, offsets, srcs, b2, out);
}

// Round 13
// 334.877 us; speedup vs baseline: 1.3485x; 1.3485x over previous
//
#include <hip/hip_runtime.h>
#include <math.h>

#define N_NODES 100000
#define F_IN    128
#define H1      8
#define C1      16
#define D1      128   // H1*C1
#define NCLS    40
#define NEG     0.2f

typedef unsigned int uint32;
typedef unsigned short ushort16;
typedef float v2f __attribute__((ext_vector_type(2)));
typedef __attribute__((ext_vector_type(8))) short bf16x8;   // 4 VGPRs, MFMA A/B frag
typedef __attribute__((ext_vector_type(4))) float f32x4;    // MFMA C/D frag

__device__ __forceinline__ ushort16 f2bf(float f) {
    unsigned int u = __float_as_uint(f);
    u += 0x7fffu + ((u >> 16) & 1u);          // round-to-nearest-even
    return (ushort16)(u >> 16);
}
__device__ __forceinline__ float bf_lo(uint32 p) { return __uint_as_float(p << 16); }
__device__ __forceinline__ float bf_hi(uint32 p) { return __uint_as_float(p & 0xffff0000u); }

#define NG 1563   // gemm blocks (64 rows each)

// W1 -> bf16 transposed+padded [128][136]; W2 -> bf16 transposed+padded
// [48][136] (cols 40-47 zero); also zeroes deg (replaces memset).
__global__ void prep_w_kernel(const float* __restrict__ W1,
                              const float* __restrict__ W2,
                              unsigned short* __restrict__ w1t,
                              unsigned short* __restrict__ w2t,
                              int* __restrict__ deg)
{
    int idx = blockIdx.x * 256 + threadIdx.x;
    if (idx < 16384) {
        int n = idx & 127, k = idx >> 7;        // coalesced read of W1[k][n]
        w1t[n * 136 + k] = f2bf(W1[k * 128 + n]);
    }
    if (idx < 6528) {                           // 48 x 136
        int c = idx / 136, k = idx - 136 * c;
        unsigned short v = 0;
        if (c < 40 && k < 128) v = f2bf(W2[k * 40 + c]);
        w2t[idx] = v;
    }
    if (idx < N_NODES) deg[idx] = 0;
}

// ---------------- fused: layer-1 MFMA GEMM(+logits) blocks + CSR-count ------
// Proven 1:4 interleave, 1 edge/thread: atomic-throughput-bound count blocks
// co-resident with LDS/MFMA-bound gemm blocks from t=0.
__global__ __launch_bounds__(256) void gemm1_count_kernel(
    const float* __restrict__ x, const unsigned short* __restrict__ w1t,
    uint32* __restrict__ h8,            // fp8 rows, N x 32 dwords
    const float* __restrict__ a_src, const float* __restrict__ a_dst,
    float* __restrict__ ssrc, float* __restrict__ sdst,
    const int* __restrict__ ei, int E,
    int* __restrict__ deg, int* __restrict__ rank)
{
    // 34816 B: holds W1^T bf16 [128][136] during MFMA, then hs fp32 [64][132]
    __shared__ __align__(16) uint32 wbuf[8704];
    const int bid = blockIdx.x;
    const int tid = threadIdx.x;
    const bool is_gemm = ((bid % 5) == 0) && (bid / 5 < NG);
    if (!is_gemm) {
        // ---------------- count path: rank[e] = old deg[dst]++ --------------
        int ng_before = bid / 5 + ((bid % 5) ? 1 : 0);   // gemm blocks < bid
        if (ng_before > NG) ng_before = NG;
        int c = bid - ng_before;
        long long e = (long long)c * 256 + tid;
        if (e < E) rank[e] = atomicAdd(&deg[ei[E + e]], 1);
        return;
    }
    const int row0 = (bid / 5) * 64;
    const int wid = tid >> 6, lane = tid & 63;

    // ---- A fragments straight from global: wave w owns rows 16w..16w+15.
    const int arow = row0 + wid * 16 + (lane & 15);
    const bool rowok = arow < N_NODES;
    const float* xp = x + (size_t)arow * 128 + 8 * (lane >> 4);
    float4 af0[4], af1[4];
#pragma unroll
    for (int s = 0; s < 4; ++s) {
        if (rowok) {
            af0[s] = *(const float4*)(xp + 32 * s);
            af1[s] = *(const float4*)(xp + 32 * s + 4);
        } else {
            af0[s] = make_float4(0.f, 0.f, 0.f, 0.f);
            af1[s] = make_float4(0.f, 0.f, 0.f, 0.f);
        }
    }
    // ---- stage W1^T bf16 into LDS (linear 34816 B copy, pad included) ----
    {
        const uint32* g = (const uint32*)w1t;
#pragma unroll
        for (int i = 0; i < 8; ++i)
            ((uint4*)wbuf)[tid + i * 256] = ((const uint4*)g)[tid + i * 256];
        wbuf[8192 + tid] = g[8192 + tid];
        wbuf[8448 + tid] = g[8448 + tid];
    }
    // ---- convert A to bf16 fragments (same k-order as B reads: 8g+j) ----
    bf16x8 a[4];
#pragma unroll
    for (int s = 0; s < 4; ++s) {
        a[s][0] = (short)f2bf(af0[s].x); a[s][1] = (short)f2bf(af0[s].y);
        a[s][2] = (short)f2bf(af0[s].z); a[s][3] = (short)f2bf(af0[s].w);
        a[s][4] = (short)f2bf(af1[s].x); a[s][5] = (short)f2bf(af1[s].y);
        a[s][6] = (short)f2bf(af1[s].z); a[s][7] = (short)f2bf(af1[s].w);
    }
    __syncthreads();
    // ---- K loop: 4 steps x 8 col-fragments = 32 MFMAs / wave ----
    f32x4 acc[8];
#pragma unroll
    for (int j = 0; j < 8; ++j)
#pragma unroll
        for (int r = 0; r < 4; ++r) acc[j][r] = 0.f;
    const unsigned short* wb = (const unsigned short*)wbuf;
    const int bc = lane & 15, ko = 8 * (lane >> 4);
#pragma unroll
    for (int s = 0; s < 4; ++s) {
#pragma unroll
        for (int j = 0; j < 8; ++j) {
            bf16x8 b = *(const bf16x8*)&wb[(16 * j + bc) * 136 + 32 * s + ko];
            acc[j] = __builtin_amdgcn_mfma_f32_16x16x32_bf16(a[s], b, acc[j], 0, 0, 0);
        }
    }
    __syncthreads();   // all MFMA operand reads of wbuf done
    // ---- write acc to hs[64][132] (C/D map: col=lane&15, row=(lane>>4)*4+r)
    float* hs = (float*)wbuf;
    const int cr0 = wid * 16 + 4 * (lane >> 4);
#pragma unroll
    for (int j = 0; j < 8; ++j)
#pragma unroll
        for (int r = 0; r < 4; ++r)
            hs[(cr0 + r) * 132 + 16 * j + bc] = acc[j][r];
    __syncthreads();
    // ---- fp8 pack: 64 rows x 16 uint2-groups, 4 tasks/thread ----
#pragma unroll
    for (int t = 0; t < 4; ++t) {
        int task = tid + t * 256;     // 0..1023
        int r = task >> 4, g = task & 15;
        if (row0 + r < N_NODES) {
            float4 va = *(const float4*)&hs[r * 132 + 8 * g];
            float4 vb = *(const float4*)&hs[r * 132 + 8 * g + 4];
            int p0 = __builtin_amdgcn_cvt_pk_fp8_f32(va.x, va.y, 0, false);
            p0     = __builtin_amdgcn_cvt_pk_fp8_f32(va.z, va.w, p0, true);
            int p1 = __builtin_amdgcn_cvt_pk_fp8_f32(vb.x, vb.y, 0, false);
            p1     = __builtin_amdgcn_cvt_pk_fp8_f32(vb.z, vb.w, p1, true);
            uint2 pk; pk.x = (uint32)p0; pk.y = (uint32)p1;
            ((uint2*)h8)[(size_t)(row0 + r) * 16 + g] = pk;
        }
    }
    // ---- logits: 64 rows x 8 heads = 512 tasks, 2 per thread ----
#pragma unroll
    for (int t = 0; t < 2; ++t) {
        int task = tid + t * 256;
        int r = task >> 3, hh = task & 7;
        if (row0 + r < N_NODES) {
            float as = 0.f, ad = 0.f;
#pragma unroll
            for (int c = 0; c < 16; ++c) {
                float v = hs[r * 132 + hh * 16 + c];
                as = fmaf(v, a_src[hh * 16 + c], as);
                ad = fmaf(v, a_dst[hh * 16 + c], ad);
            }
            ssrc[(row0 + r) * 8 + hh] = as;
            sdst[(row0 + r) * 8 + hh] = ad;
        }
    }
}

// block-local inclusive scan (256/block) + raw block sums
__global__ void scan1_kernel(const int* __restrict__ deg,
                             int* __restrict__ incl,
                             int* __restrict__ bsum)
{
    __shared__ int tmp[256];
    int i = blockIdx.x * 256 + threadIdx.x;
    int v = (i < N_NODES) ? deg[i] : 0;
    tmp[threadIdx.x] = v;
    __syncthreads();
    for (int o = 1; o < 256; o <<= 1) {
        int t = (threadIdx.x >= (unsigned)o) ? tmp[threadIdx.x - o] : 0;
        __syncthreads();
        tmp[threadIdx.x] += t;
        __syncthreads();
    }
    if (i < N_NODES) incl[i] = tmp[threadIdx.x];
    if (threadIdx.x == 255) bsum[blockIdx.x] = tmp[255];
}

// offsets[i+1] = incl[i] + prefix(bsum, block); each block sums its own
// prefix of the raw block sums — replaces scan2+scan3.
__global__ void scan3_kernel(const int* __restrict__ incl,
                             const int* __restrict__ bsum,
                             int* __restrict__ offsets)
{
    __shared__ int red[4];
    int pre = 0;
    for (int i = threadIdx.x; i < blockIdx.x; i += 256) pre += bsum[i];
#pragma unroll
    for (int o = 32; o > 0; o >>= 1) pre += __shfl_xor(pre, o);
    if ((threadIdx.x & 63) == 0) red[threadIdx.x >> 6] = pre;
    __syncthreads();
    int total = red[0] + red[1] + red[2] + red[3];
    int i = blockIdx.x * 256 + threadIdx.x;
    if (i < N_NODES) offsets[i + 1] = incl[i] + total;
    if (i == 0) offsets[0] = 0;
}

// atomic-free scatter using precomputed rank
__global__ void scatter_kernel(const int* __restrict__ ei, int E,
                               const int* __restrict__ offsets,
                               const int* __restrict__ rank,
                               int* __restrict__ srcs)
{
    int e = blockIdx.x * blockDim.x + threadIdx.x;
    if (e >= E) return;
    int s = ei[e], d = ei[E + e];
    srcs[offsets[d] + rank[e]] = s;
}

// ---------------- layer 1 gather: one wave per dst node (fp8 h rows) --------
// 128-thread blocks. Widened inner loop: 16 lanes cover a row in uint2s
// (8 ch/lane), 4 edges in flight per step -> 2 steps / 8-edge chunk.
__global__ void gather1_kernel(const uint32* __restrict__ h8,   // N x 32 dwords
                               const float* __restrict__ ssrc,
                               const float* __restrict__ sdst,
                               const int* __restrict__ offsets,
                               const int* __restrict__ srcs,
                               const float* __restrict__ b1,
                               uint32* __restrict__ h1b)        // N x 64 dwords
{
    __shared__ uint2 sw[2][64];
    int d = (blockIdx.x * blockDim.x + threadIdx.x) >> 6;
    int lane = threadIdx.x & 63;
    int wid = (threadIdx.x >> 6) & 1;
    if (d >= N_NODES) return;
    const int hw = lane & 7;            // head in weight phase
    const int u2 = lane & 15;           // uint2 in row: channels 8u2..8u2+7
    const int qt = lane >> 4;           // quarter: which of 4 in-flight edges
    const int hc = u2 >> 1;             // head of my channels
    const float sd_w = sdst[d * H1 + hw];

    float a0 = 0.f, a1 = 0.f, a2 = 0.f, a3 = 0.f;
    float a4 = 0.f, a5 = 0.f, a6 = 0.f, a7 = 0.f;
    float wsum = 0.f;

    // (s,w) staging slot for my (quarter, head): edge of slot = 4t+qt
    const uint2* swp = &sw[wid][(qt << 3) | hc];
    const uint2* h8v = (const uint2*)h8;       // rows of 16 uint2
    const int beg = offsets[d], end = offsets[d + 1];
    for (int base = beg; base < end; base += 8) {
        int cnt = end - base; if (cnt > 8) cnt = 8;
        int s_l = 0; float w_l = 0.f;
        if ((lane >> 3) < cnt) {
            s_l = srcs[base + (lane >> 3)];
            float lg = ssrc[s_l * H1 + hw] + sd_w;
            lg = lg >= 0.f ? lg : NEG * lg;
            w_l = __expf(lg);
        }
        wsum += w_l;
        sw[wid][lane] = make_uint2((uint32)s_l, __float_as_uint(w_l));
        asm volatile("s_waitcnt lgkmcnt(0)" ::: "memory");
#pragma unroll
        for (int t = 0; t < 2; ++t) {       // slots >= cnt carry w=0, s=0
            uint2 q = swp[32 * t];
            float w = __uint_as_float(q.y);
            uint2 p = h8v[(size_t)q.x * 16 + u2];
            v2f xl = __builtin_amdgcn_cvt_pk_f32_fp8((int)p.x, false);
            v2f xh = __builtin_amdgcn_cvt_pk_f32_fp8((int)p.x, true);
            v2f yl = __builtin_amdgcn_cvt_pk_f32_fp8((int)p.y, false);
            v2f yh = __builtin_amdgcn_cvt_pk_f32_fp8((int)p.y, true);
            a0 = fmaf(w, xl[0], a0); a1 = fmaf(w, xl[1], a1);
            a2 = fmaf(w, xh[0], a2); a3 = fmaf(w, xh[1], a3);
            a4 = fmaf(w, yl[0], a4); a5 = fmaf(w, yl[1], a5);
            a6 = fmaf(w, yh[0], a6); a7 = fmaf(w, yh[1], a7);
        }
    }
    // head-wise weight totals: reduce over the 8 edge-slot groups (bits 3..5)
    wsum += __shfl_xor(wsum, 8);
    wsum += __shfl_xor(wsum, 16);
    wsum += __shfl_xor(wsum, 32);
    float wtot = __shfl(wsum, hc);       // before divergence
    // cross-quarter accumulator reduce (bits 4,5)
    a0 += __shfl_xor(a0, 16); a0 += __shfl_xor(a0, 32);
    a1 += __shfl_xor(a1, 16); a1 += __shfl_xor(a1, 32);
    a2 += __shfl_xor(a2, 16); a2 += __shfl_xor(a2, 32);
    a3 += __shfl_xor(a3, 16); a3 += __shfl_xor(a3, 32);
    a4 += __shfl_xor(a4, 16); a4 += __shfl_xor(a4, 32);
    a5 += __shfl_xor(a5, 16); a5 += __shfl_xor(a5, 32);
    a6 += __shfl_xor(a6, 16); a6 += __shfl_xor(a6, 32);
    a7 += __shfl_xor(a7, 16); a7 += __shfl_xor(a7, 32);
    if (lane < 16) {
        // self-loop weight + contribution for my head
        float lgs = ssrc[d * H1 + hc] + sdst[d * H1 + hc];
        lgs = lgs >= 0.f ? lgs : NEG * lgs;
        float wself = __expf(lgs);
        uint2 p = h8v[(size_t)d * 16 + u2];
        v2f xl = __builtin_amdgcn_cvt_pk_f32_fp8((int)p.x, false);
        v2f xh = __builtin_amdgcn_cvt_pk_f32_fp8((int)p.x, true);
        v2f yl = __builtin_amdgcn_cvt_pk_f32_fp8((int)p.y, false);
        v2f yh = __builtin_amdgcn_cvt_pk_f32_fp8((int)p.y, true);
        a0 = fmaf(wself, xl[0], a0); a1 = fmaf(wself, xl[1], a1);
        a2 = fmaf(wself, xh[0], a2); a3 = fmaf(wself, xh[1], a3);
        a4 = fmaf(wself, yl[0], a4); a5 = fmaf(wself, yl[1], a5);
        a6 = fmaf(wself, yh[0], a6); a7 = fmaf(wself, yh[1], a7);
        float inv = 1.f / (wself + wtot + 1e-16f);
        float4 bb0 = ((const float4*)b1)[2 * u2];
        float4 bb1 = ((const float4*)b1)[2 * u2 + 1];
        float r0 = fmaf(a0, inv, bb0.x); r0 = r0 > 0.f ? r0 : 0.f;
        float r1 = fmaf(a1, inv, bb0.y); r1 = r1 > 0.f ? r1 : 0.f;
        float r2 = fmaf(a2, inv, bb0.z); r2 = r2 > 0.f ? r2 : 0.f;
        float r3 = fmaf(a3, inv, bb0.w); r3 = r3 > 0.f ? r3 : 0.f;
        float r4 = fmaf(a4, inv, bb1.x); r4 = r4 > 0.f ? r4 : 0.f;
        float r5 = fmaf(a5, inv, bb1.y); r5 = r5 > 0.f ? r5 : 0.f;
        float r6 = fmaf(a6, inv, bb1.z); r6 = r6 > 0.f ? r6 : 0.f;
        float r7 = fmaf(a7, inv, bb1.w); r7 = r7 > 0.f ? r7 : 0.f;
        uint4 pk;
        pk.x = ((uint32)f2bf(r1) << 16) | (uint32)f2bf(r0);
        pk.y = ((uint32)f2bf(r3) << 16) | (uint32)f2bf(r2);
        pk.z = ((uint32)f2bf(r5) << 16) | (uint32)f2bf(r4);
        pk.w = ((uint32)f2bf(r7) << 16) | (uint32)f2bf(r6);
        ((uint4*)(h1b + (size_t)d * 64))[u2] = pk;
    }
}

// ---------------- layer 2 GEMM (bf16 MFMA) + logits, fused ------------------
__global__ __launch_bounds__(256) void gemm2_kernel(
    const uint32* __restrict__ h1b, const unsigned short* __restrict__ w2t,
    uint32* __restrict__ h2f8,          // fp8 rows, N x 10 dwords
    const float* __restrict__ a_src, const float* __restrict__ a_dst,
    float* __restrict__ ssrc, float* __restrict__ sdst)
{
    __shared__ __align__(16) unsigned short w2s[6528];   // 13056 B
    const int row0 = blockIdx.x * 64;
    const int tid = threadIdx.x;
    const int wid = tid >> 6, lane = tid & 63;
    const int bc = lane & 15, g = lane >> 4;

    // ---- stage W2^T bf16 (3264 dwords) ----
    {
        const uint32* gs = (const uint32*)w2t;
        uint32* wsd = (uint32*)w2s;
        for (int i = tid; i < 3264; i += 256) wsd[i] = gs[i];
    }
    // ---- A fragments: wave w owns rows 16w..16w+15, direct bf16 loads ----
    const int arow = row0 + wid * 16 + bc;
    const bool rowok = arow < N_NODES;
    bf16x8 a[4];
#pragma unroll
    for (int s = 0; s < 4; ++s) {
        uint4 v = make_uint4(0u, 0u, 0u, 0u);
        if (rowok) v = *(const uint4*)&h1b[(size_t)arow * 64 + 16 * s + 4 * g];
        a[s] = *(bf16x8*)&v;
    }
    __syncthreads();
    // ---- 4 k-steps x 3 col-fragments = 12 MFMA / wave ----
    f32x4 acc[3];
#pragma unroll
    for (int j = 0; j < 3; ++j)
#pragma unroll
        for (int r = 0; r < 4; ++r) acc[j][r] = 0.f;
#pragma unroll
    for (int s = 0; s < 4; ++s) {
#pragma unroll
        for (int j = 0; j < 3; ++j) {
            bf16x8 b = *(const bf16x8*)&w2s[(16 * j + bc) * 136 + 32 * s + 8 * g];
            acc[j] = __builtin_amdgcn_mfma_f32_16x16x32_bf16(a[s], b, acc[j], 0, 0, 0);
        }
    }
    // ---- h2 fp8 pack: channels 4k..4k+3 live in adjacent bc-lanes ----
    const int cr0 = wid * 16 + 4 * g;
#pragma unroll
    for (int j = 0; j < 3; ++j)
#pragma unroll
        for (int r = 0; r < 4; ++r) {
            float v0 = acc[j][r];
            float v1 = __shfl_xor(v0, 1);
            float v2 = __shfl_xor(v0, 2);
            float v3 = __shfl_xor(v0, 3);
            if ((bc & 3) == 0) {
                int dw = 4 * j + (bc >> 2);          // dword index in row
                int row = row0 + cr0 + r;
                if (dw < 10 && row < N_NODES) {
                    int p = __builtin_amdgcn_cvt_pk_fp8_f32(v0, v1, 0, false);
                    p     = __builtin_amdgcn_cvt_pk_fp8_f32(v2, v3, p, true);
                    h2f8[(size_t)row * 10 + dw] = (uint32)p;
                }
            }
        }
    // ---- logits via bc-butterflies: 16 bc-lanes hold all cols of 4 rows ----
    float avs[3], avd[3];
#pragma unroll
    for (int j = 0; j < 3; ++j) {
        int col = 16 * j + bc;
        avs[j] = (col < NCLS) ? a_src[col] : 0.f;
        avd[j] = (col < NCLS) ? a_dst[col] : 0.f;
    }
    float ps[4], pd[4];
#pragma unroll
    for (int r = 0; r < 4; ++r) {
        float s_ = acc[0][r] * avs[0];
        s_ = fmaf(acc[1][r], avs[1], s_);
        s_ = fmaf(acc[2][r], avs[2], s_);
        float d_ = acc[0][r] * avd[0];
        d_ = fmaf(acc[1][r], avd[1], d_);
        d_ = fmaf(acc[2][r], avd[2], d_);
        ps[r] = s_; pd[r] = d_;
    }
#pragma unroll
    for (int o = 1; o < 16; o <<= 1) {
#pragma unroll
        for (int r = 0; r < 4; ++r) {
            ps[r] += __shfl_xor(ps[r], o);
            pd[r] += __shfl_xor(pd[r], o);
        }
    }
    if (bc < 4) {
        int row = row0 + cr0 + bc;
        if (row < N_NODES) {
            float vs = bc == 0 ? ps[0] : bc == 1 ? ps[1] : bc == 2 ? ps[2] : ps[3];
            float vd = bc == 0 ? pd[0] : bc == 1 ? pd[1] : bc == 2 ? pd[2] : pd[3];
            ssrc[row] = vs;
            sdst[row] = vd;
        }
    }
}

// ---------------- layer 2 gather + log_softmax: one wave per node (fp8) -----
__global__ void gather2_kernel(const uint32* __restrict__ h2f8, // N x 10 dwords
                               const float* __restrict__ ssrc,
                               const float* __restrict__ sdst,
                               const int* __restrict__ offsets,
                               const int* __restrict__ srcs,
                               const float* __restrict__ b2,
                               float* __restrict__ out)
{
    __shared__ uint2 sw[2][64];
    __shared__ __align__(16) float4 pacc[2][64];
    int d = (blockIdx.x * blockDim.x + threadIdx.x) >> 6;
    int lane = threadIdx.x & 63;
    int wid = (threadIdx.x >> 6) & 1;
    if (d >= N_NODES) return;
    const float sd = sdst[d];
    const int g = lane / 10;              // group 0..6 (g<6 accumulate)
    const int c = lane - 10 * g;          // dword within row: channels 4c..4c+3
    const bool act = lane < 10;           // lanes that own the output
    float acc0 = 0.f, acc1 = 0.f, acc2 = 0.f, acc3 = 0.f, wl = 0.f;

    // self-loop (output lanes only)
    float ws_self;
    {
        float lg = ssrc[d] + sd; lg = lg >= 0.f ? lg : NEG * lg;
        ws_self = __expf(lg);
        if (act) {
            uint32 p = h2f8[(size_t)d * 10 + lane];
            v2f lo = __builtin_amdgcn_cvt_pk_f32_fp8((int)p, false);
            v2f hi = __builtin_amdgcn_cvt_pk_f32_fp8((int)p, true);
            acc0 = ws_self * lo[0]; acc1 = ws_self * lo[1];
            acc2 = ws_self * hi[0]; acc3 = ws_self * hi[1];
        }
    }
    const int beg = offsets[d], end = offsets[d + 1];
    for (int base = beg; base < end; base += 64) {
        int cnt = end - base; if (cnt > 64) cnt = 64;
        int s_l = 0; float w_l = 0.f;
        if (lane < cnt) {
            s_l = srcs[base + lane];
            float lg = ssrc[s_l] + sd; lg = lg >= 0.f ? lg : NEG * lg;
            w_l = __expf(lg);
        }
        wl += w_l;
        sw[wid][lane] = make_uint2((uint32)s_l, __float_as_uint(w_l));
        asm volatile("s_waitcnt lgkmcnt(0)" ::: "memory");
        for (int j = 0; j < cnt; j += 6) {
            int jj = j + g;
            uint2 q = sw[wid][jj & 63];
            float w = ((g < 6) & (jj < cnt)) ? __uint_as_float(q.y) : 0.f;
            uint32 p = h2f8[(size_t)q.x * 10 + c];
            v2f lo = __builtin_amdgcn_cvt_pk_f32_fp8((int)p, false);
            v2f hi = __builtin_amdgcn_cvt_pk_f32_fp8((int)p, true);
            acc0 = fmaf(w, lo[0], acc0);
            acc1 = fmaf(w, lo[1], acc1);
            acc2 = fmaf(w, hi[0], acc2);
            acc3 = fmaf(w, hi[1], acc3);
        }
    }
    // denominator: one full-wave reduce at the end
    float t = wl;
#pragma unroll
    for (int o = 32; o > 0; o >>= 1) t += __shfl_xor(t, o);
    float ws = ws_self + t;
    // cross-group accumulator reduce via LDS (partials at lanes c + 10k)
    float4 mine; mine.x = acc0; mine.y = acc1; mine.z = acc2; mine.w = acc3;
    pacc[wid][lane] = mine;
    asm volatile("s_waitcnt lgkmcnt(0)" ::: "memory");
    float l0 = -INFINITY, l1 = -INFINITY, l2 = -INFINITY, l3 = -INFINITY;
    if (act) {
        float4 s0 = pacc[wid][lane];
        float4 s1 = pacc[wid][lane + 10];
        float4 s2 = pacc[wid][lane + 20];
        float4 s3 = pacc[wid][lane + 30];
        float4 s4 = pacc[wid][lane + 40];
        float4 s5 = pacc[wid][lane + 50];
        float a0 = s0.x + s1.x + s2.x + s3.x + s4.x + s5.x;
        float a1 = s0.y + s1.y + s2.y + s3.y + s4.y + s5.y;
        float a2 = s0.z + s1.z + s2.z + s3.z + s4.z + s5.z;
        float a3 = s0.w + s1.w + s2.w + s3.w + s4.w + s5.w;
        float inv = 1.f / (ws + 1e-16f);
        l0 = fmaf(a0, inv, b2[4 * lane + 0]);
        l1 = fmaf(a1, inv, b2[4 * lane + 1]);
        l2 = fmaf(a2, inv, b2[4 * lane + 2]);
        l3 = fmaf(a3, inv, b2[4 * lane + 3]);
    }
    // softmax over 10 active lanes: 16-lane butterflies suffice
    float m = fmaxf(fmaxf(l0, l1), fmaxf(l2, l3));
#pragma unroll
    for (int o = 8; o > 0; o >>= 1) m = fmaxf(m, __shfl_xor(m, o));
    float ex = act ? (__expf(l0 - m) + __expf(l1 - m) + __expf(l2 - m) + __expf(l3 - m)) : 0.f;
#pragma unroll
    for (int o = 8; o > 0; o >>= 1) ex += __shfl_xor(ex, o);
    float lse = __logf(ex) + m;
    if (act) {
        float4 r;
        r.x = l0 - lse; r.y = l1 - lse; r.z = l2 - lse; r.w = l3 - lse;
        ((float4*)(out + (size_t)d * NCLS))[lane] = r;
    }
}

extern "C" void kernel_launch(void* const* d_in, const int* in_sizes, int n_in,
                              void* d_out, int out_size, void* d_ws, size_t ws_size,
                              hipStream_t stream)
{
    const float* x   = (const float*)d_in[0];
    const int*   ei  = (const int*)  d_in[1];
    const float* W1  = (const float*)d_in[2];
    const float* as1 = (const float*)d_in[3];
    const float* ad1 = (const float*)d_in[4];
    const float* b1  = (const float*)d_in[5];
    const float* W2  = (const float*)d_in[6];
    const float* as2 = (const float*)d_in[7];
    const float* ad2 = (const float*)d_in[8];
    const float* b2  = (const float*)d_in[9];
    float* out = (float*)d_out;
    const int E = in_sizes[1] / 2;

    float* ws = (float*)d_ws;
    size_t off = 0;
    uint32* h1f8 = (uint32*)(ws + off); off += (size_t)N_NODES * 32;  // fp8 N x 128
    uint32* h1b = (uint32*)(ws + off); off += (size_t)N_NODES * 64;   // bf16 N x 128 packed
    float* ss1  = ws + off; off += (size_t)N_NODES * H1;
    float* sd1  = ws + off; off += (size_t)N_NODES * H1;
    uint32* h2f8 = (uint32*)(ws + off); off += (size_t)N_NODES * 10;  // fp8 N x 40
    float* ss2  = ws + off; off += N_NODES;
    float* sd2  = ws + off; off += N_NODES;
    unsigned short* w1t = (unsigned short*)(ws + off); off += 8704;   // bf16 W1^T [128][136]
    unsigned short* w2t = (unsigned short*)(ws + off); off += 3264;   // bf16 W2^T [48][136]
    int* ib = (int*)(ws + off);
    size_t ioff = 0;
    int* deg     = ib + ioff; ioff += N_NODES;      // zeroed in prep_w_kernel
    int* incl    = ib + ioff; ioff += N_NODES;
    int* offsets = ib + ioff; ioff += N_NODES + 1;
    int* bsum    = ib + ioff; ioff += 512;
    int* rank    = ib + ioff; ioff += E;
    int* srcs    = ib + ioff; ioff += E;

    const int nb = (N_NODES + 255) / 256;           // 391
    const int nc = (E + 255) / 256;                 // count blocks (6250)

    // W1/W2 -> bf16 transposed+padded + deg zeroing
    prep_w_kernel<<<nb, 256, 0, stream>>>(W1, W2, w1t, w2t, deg);

    // fused layer-1 MFMA gemm(+logits) + CSR count (proven 1:4 interleave)
    gemm1_count_kernel<<<NG + nc, 256, 0, stream>>>(x, w1t, h1f8, as1, ad1,
                                                    ss1, sd1, ei, E, deg, rank);
    // CSR finish
    scan1_kernel<<<nb, 256, 0, stream>>>(deg, incl, bsum);
    scan3_kernel<<<nb, 256, 0, stream>>>(incl, bsum, offsets);
    scatter_kernel<<<(E + 255) / 256, 256, 0, stream>>>(ei, E, offsets, rank, srcs);

    // layer 1 gather (128-thread blocks, widened uint2 inner loop)
    gather1_kernel<<<(N_NODES * 64 + 127) / 128, 128, 0, stream>>>(h1f8, ss1, sd1, offsets, srcs, b1, h1b);

    // layer 2 (MFMA gemm + fp8 h2 pack + shuffle logits fused)
    gemm2_kernel<<<(N_NODES + 63) / 64, 256, 0, stream>>>(h1b, w2t, h2f8, as2, ad2, ss2, sd2);
    gather2_kernel<<<(N_NODES * 64 + 127) / 128, 128, 0, stream>>>(h2f8, ss2, sd2, offsets, srcs, b2, out);
}